// Round 12
// baseline (220.082 us; speedup 1.0000x reference)
//
#include <hip/hip_runtime.h>
#include <hip/hip_bf16.h>

typedef __hip_bfloat16 bf16;
typedef short bf16x8 __attribute__((ext_vector_type(8)));
typedef float f32x4 __attribute__((ext_vector_type(4)));

#define CC 16
#define PP 256
#define DMH 512
#define DIH 1024
#define MM (CC*PP)   /* 4096 rows (c,p) */
#define NST 16
#define NDT 32
#define LOG2E 1.44269504088896f

__device__ __forceinline__ float b2f(bf16 v){ return __bfloat162float(v); }
__device__ __forceinline__ bf16  f2b(float v){ return __float2bfloat16(v); }
__device__ __forceinline__ float us2f(ushort u){ bf16 h; *(ushort*)&h = u; return __bfloat162float(h); }

// fast tanh-gelu: tanh(u) = 1 - 2/(exp(2u)+1); exact limits at +-inf
__device__ __forceinline__ float geluf(float x){
  const float u = x*(0.7978845608028654f + 0.035677408136300125f*x*x);
  const float e = __builtin_amdgcn_exp2f(2.885390081777927f*u);   // exp(2u)
  const float t = 1.0f - 2.0f*__builtin_amdgcn_rcpf(e + 1.0f);
  return 0.5f*x*(1.0f + t);
}
// softplus via v_exp/v_log: ln(1+e^x) = ln2 * log2(1 + exp2(x*log2e))
__device__ __forceinline__ float softplusf(float x){
  if (x > 20.0f) return x;
  const float e = __builtin_amdgcn_exp2f(x * LOG2E);
  return 0.6931471805599453f * __builtin_amdgcn_logf(1.0f + e);
}

__device__ __forceinline__ void g2l16(const bf16* g, bf16* l){
  __builtin_amdgcn_global_load_lds(
      (const __attribute__((address_space(1))) void*)g,
      (__attribute__((address_space(3))) void*)(uint32_t)(uintptr_t)l,
      16, 0, 0);
}

// ---------------- fused prep: casts + conv repack (+cb2p partials) + transpose + dtw --
__global__ void prep_all(const float* __restrict__ x, const float* __restrict__ in_w,
                         const float* __restrict__ out_w, const float* __restrict__ param_w,
                         const float* __restrict__ conv_w, const float* __restrict__ dt_w,
                         const float* __restrict__ in_b, const float* __restrict__ conv_b,
                         float* __restrict__ cb2p,
                         bf16* __restrict__ xbf, bf16* __restrict__ inwz,
                         bf16* __restrict__ outwb, bf16* __restrict__ pwb,
                         bf16* __restrict__ cwT, bf16* __restrict__ inwT,
                         bf16* __restrict__ dtwb)
{
  const int b = blockIdx.x, tid = threadIdx.x;
  if (b < 3136){
    const float* src; bf16* dst; int i;
    if (b < 2048)      { src = x;                       dst = xbf;   i = b*256 + tid; }
    else if (b < 2560) { src = in_w + (size_t)DIH*DMH;  dst = inwz;  i = (b-2048)*256 + tid; }
    else if (b < 3072) { src = out_w;                   dst = outwb; i = (b-2560)*256 + tid; }
    else               { src = param_w;                 dst = pwb;   i = (b-3072)*256 + tid; }
    float4 v = ((const float4*)src)[i];
    bf16 o[4] = {f2b(v.x), f2b(v.y), f2b(v.z), f2b(v.w)};
    *(ushort4*)&dst[(size_t)i*4] = *(const ushort4*)o;
  } else if (b < 7232){
    const size_t idx = (size_t)(b-3136)*256 + tid;      // o*1024 + i
    const float4 v = *(const float4*)(conv_w + idx*4);  // [o][i][tap] -> [tap][o][i]
    cwT[idx]                     = f2b(v.x);
    cwT[(size_t)DIH*DIH   + idx] = f2b(v.y);
    cwT[(size_t)2*DIH*DIH + idx] = f2b(v.z);
    cwT[(size_t)3*DIH*DIH + idx] = f2b(v.w);
    // folded bias partial (no atomics): cb2p[sub][o] = sum over this block's i-range
    __shared__ float ls[4];
    const int i = (int)(idx & 1023);
    float acc = (v.x + v.y + v.z + v.w) * in_b[i];
    for (int off = 32; off; off >>= 1) acc += __shfl_down(acc, off);
    if ((tid & 63) == 0) ls[tid >> 6] = acc;
    __syncthreads();
    if (tid == 0){
      const int o   = (int)(idx >> 10);
      const int sub = (b - 3136) & 3;
      float tot = ls[0] + ls[1] + ls[2] + ls[3];
      if (sub == 0) tot += conv_b[o];
      cb2p[sub*DIH + o] = tot;
    }
  } else if (b < 7360){
    // in_w xi-half [i<1024][m<512] -> inwT [m][i], 64x64 LDS tile
    __shared__ float T[64][65];
    const int b2 = b - 7232;
    const int i0 = (b2 >> 3)*64, m0 = (b2 & 7)*64;
    const int r = tid >> 2, c0 = (tid & 3)*16;
    #pragma unroll
    for (int t = 0; t < 4; t++){
      float4 v = *(const float4*)&in_w[(size_t)(i0 + r)*DMH + m0 + c0 + t*4];
      T[r][c0+t*4+0] = v.x; T[r][c0+t*4+1] = v.y;
      T[r][c0+t*4+2] = v.z; T[r][c0+t*4+3] = v.w;
    }
    __syncthreads();
    bf16 o[16];
    #pragma unroll
    for (int t = 0; t < 16; t++) o[t] = f2b(T[c0 + t][r]);
    *(ushort4*)&inwT[(size_t)(m0 + r)*DIH + i0 + c0]      = *(const ushort4*)&o[0];
    *(ushort4*)&inwT[(size_t)(m0 + r)*DIH + i0 + c0 + 4]  = *(const ushort4*)&o[4];
    *(ushort4*)&inwT[(size_t)(m0 + r)*DIH + i0 + c0 + 8]  = *(const ushort4*)&o[8];
    *(ushort4*)&inwT[(size_t)(m0 + r)*DIH + i0 + c0 + 12] = *(const ushort4*)&o[12];
  } else {
    // dt_w [1024][32] fp32 -> dtwb [1024][64] bf16, cols 32..63 zero (K=64 pad)
    const int idx4 = (b-7360)*256 + tid;          // 0..16383
    const int d = idx4 >> 4, k4 = (idx4 & 15)*4;
    bf16 o[4] = {};
    if (k4 < 32){
      const float4 v = *(const float4*)&dt_w[(size_t)d*NDT + k4];
      o[0]=f2b(v.x); o[1]=f2b(v.y); o[2]=f2b(v.z); o[3]=f2b(v.w);
    }
    *(ushort4*)&dtwb[(size_t)d*64 + k4] = *(const ushort4*)o;
  }
}

// ---------------- MFMA GEMM: C[m,n] = epi( sum_k A[m,k]*B[n,k] + bias[n] ) -------------
// LDS XOR-swizzle (T2, gload_lds-compatible): linear LDS dest, pre-swizzled global
// source chunk, same XOR on the ds_read side.
#define TBK 64

template<int EPI, int NFRAG>
__launch_bounds__(256)
__global__ void mfma_gemm(const bf16* __restrict__ A, int lda,
                          const bf16* __restrict__ B, int ldb,
                          const float* __restrict__ bias,
                          float* __restrict__ outF,
                          bf16* __restrict__ outB0,
                          int ldo, int K, int azs, int ozs, int kzs)
{
  __shared__ bf16 As[128*TBK];           // 16 KB
  __shared__ bf16 Bs[32*NFRAG*TBK];      // 4/8 KB
  const int tid  = threadIdx.x;
  const int lane = tid & 63;
  const int wave = tid >> 6;
  const int wr = (wave >> 1) * 64;
  const int wc = (wave & 1) * 16 * NFRAG;
  const int mBase = blockIdx.x * 128;
  const int nBase = blockIdx.y * (32*NFRAG);
  A += (size_t)blockIdx.z * azs;
  const int nOff = blockIdx.z * ozs;
  const int koff = blockIdx.z * kzs;

  f32x4 acc[4][NFRAG] = {};

  for (int k0 = 0; k0 < K; k0 += TBK) {
    __syncthreads();
    #pragma unroll
    for (int it = 0; it < 4; it++) {      // As: 1024 chunks of 16B
      const int idx = it*256 + tid;
      const int r = idx >> 3;
      const int cs = (idx & 7) ^ (r & 7);         // pre-swizzled source chunk
      const bf16* ga = A + (size_t)(mBase + r)*lda + koff + k0 + cs*8;
      g2l16(ga, &As[(size_t)idx*8]);
    }
    #pragma unroll
    for (int it = 0; it < NFRAG; it++) {  // Bs: 256*NFRAG chunks of 16B
      const int idx = it*256 + tid;
      const int r = idx >> 3;
      const int cs = (idx & 7) ^ (r & 7);
      const bf16* gb = B + (size_t)(nBase + r)*ldb + koff + k0 + cs*8;
      g2l16(gb, &Bs[(size_t)idx*8]);
    }
    __syncthreads();
    #pragma unroll
    for (int ks = 0; ks < 2; ks++) {
      bf16x8 af[4], bfr[NFRAG];
      #pragma unroll
      for (int r = 0; r < 4; r++){
        const int rr = wr + r*16 + (lane & 15);
        const int ch = (ks*4 + (lane>>4)) ^ (rr & 7);
        af[r] = *(const bf16x8*)&As[rr*TBK + ch*8];
      }
      #pragma unroll
      for (int c = 0; c < NFRAG; c++){
        const int rn = wc + c*16 + (lane & 15);
        const int ch = (ks*4 + (lane>>4)) ^ (rn & 7);
        bfr[c] = *(const bf16x8*)&Bs[rn*TBK + ch*8];
      }
      #pragma unroll
      for (int r = 0; r < 4; r++)
        #pragma unroll
        for (int c = 0; c < NFRAG; c++)
          acc[r][c] = __builtin_amdgcn_mfma_f32_16x16x32_bf16(af[r], bfr[c], acc[r][c], 0, 0, 0);
    }
  }

  const int col0 = lane & 15;
  const int row0 = (lane >> 4) * 4;
  #pragma unroll
  for (int r = 0; r < 4; r++) {
    #pragma unroll
    for (int c = 0; c < NFRAG; c++) {
      #pragma unroll
      for (int reg = 0; reg < 4; reg++) {
        const int m = mBase + wr + r*16 + row0 + reg;
        const int n = nBase + wc + c*16 + col0;
        const float av = acc[r][c][reg];
        if (EPI == 0) {
          outF[(size_t)m*ldo + n] = av + bias[n];
        } else if (EPI == 2) {
          outB0[(size_t)m*ldo + n] = f2b(geluf(geluf(av + bias[n])));
        } else if (EPI == 3) {
          outB0[(size_t)m*ldo + n + nOff] = f2b(av);
        } else if (EPI == 5) {
          // dt = softplus(av + dt_b[n]) -> bf16 dt-only plane (dt*xi done in scan)
          const float dtv = softplusf(av + bias[n]);
          bf16 dh = f2b(dtv);
          ((ushort*)outB0)[(size_t)m*ldo + n] = *(const ushort*)&dh;
        } else if (EPI == 7) {
          // fused param epilogue: n<32 -> xdbb (bf16 dt-GEMM input);
          // n>=32 -> bcg (fp32 B|C) + zero-pad xdbb col (K=64 pad for dt GEMM)
          const float vv = av + bias[n];
          if (n < 32) {
            bf16 dh = f2b(vv);
            ((ushort*)outB0)[(size_t)m*64 + n] = *(const ushort*)&dh;
          } else {
            ((ushort*)outB0)[(size_t)m*64 + n] = 0;
            outF[(size_t)m*32 + (n - 32)] = vv;
          }
        }
      }
    }
  }
}

// ---------------- halo-tiled conv GEMM: xi = gelu( sum_tap x[clamp]@Wf_tap^T + cb2 ) ---
// Stages the A panel ONCE per K-step (132-row halo tile, edge-clamped) and keeps 4
// tap-accumulators. bias is cb2p[4][1024] partials (summed here; no atomics upstream).
__launch_bounds__(256)
__global__ void mfma_conv(const bf16* __restrict__ A,   // xbf [4096][512]
                          const bf16* __restrict__ B,   // Wfb [1024][4*512] (o, tap*512+m)
                          const float* __restrict__ bias, // cb2p [4][1024]
                          bf16* __restrict__ outB)      // xi [4096][1024]
{
  __shared__ bf16 As[132*64];        // halo rows h=0..131 -> p = clamp(q-2+h, 0, 255)
  __shared__ bf16 Bs[128*64];        // (tap*32+o) x 64
  const int tid = threadIdx.x;
  const int lane = tid & 63;
  const int wave = tid >> 6;
  const int wr = (wave >> 1) * 64;
  const int wc = (wave & 1) * 16;
  const int mBase = blockIdx.x * 128;
  const int nBase = blockIdx.y * 32;
  const int cc = mBase >> 8;
  const int q  = mBase & 255;

  f32x4 acc[4][4] = {};   // [r][tap]

  for (int k0 = 0; k0 < DMH; k0 += 64) {
    __syncthreads();
    // stage A halo: 132 rows x 8 chunks = 1056 (swizzle keyed on halo row h)
    #pragma unroll
    for (int it = 0; it < 5; it++) {
      const int idx = it*256 + tid;
      if (it < 4 || idx < 1056) {
        const int h = idx >> 3;
        const int cs = (idx & 7) ^ (h & 7);
        int p = q - 2 + h;
        p = min(max(p, 0), PP-1);
        g2l16(A + ((size_t)(cc*PP + p))*DMH + k0 + cs*8, &As[(size_t)idx*8]);
      }
    }
    // stage B: rows (tap*32+o), 128 x 8 chunks = 1024
    #pragma unroll
    for (int it = 0; it < 4; it++) {
      const int idx = it*256 + tid;
      const int r = idx >> 3;             // tap*32 + o
      const int tap = r >> 5, o = r & 31;
      const int cs = (idx & 7) ^ (r & 7);
      g2l16(B + (size_t)(nBase + o)*(4*DMH) + tap*DMH + k0 + cs*8, &Bs[(size_t)idx*8]);
    }
    __syncthreads();
    #pragma unroll
    for (int ks = 0; ks < 2; ks++) {
      #pragma unroll
      for (int t = 0; t < 4; t++) {
        bf16x8 bft;
        {
          const int rn = t*32 + wc + (lane & 15);
          const int ch = (ks*4 + (lane>>4)) ^ (rn & 7);
          bft = *(const bf16x8*)&Bs[rn*64 + ch*8];
        }
        #pragma unroll
        for (int r = 0; r < 4; r++) {
          const int h = wr + r*16 + (lane & 15) + t;   // output row m_local + tap
          const int ch = (ks*4 + (lane>>4)) ^ (h & 7);
          bf16x8 af = *(const bf16x8*)&As[h*64 + ch*8];
          acc[r][t] = __builtin_amdgcn_mfma_f32_16x16x32_bf16(af, bft, acc[r][t], 0, 0, 0);
        }
      }
    }
  }
  const int col0 = lane & 15;
  const int row0 = (lane >> 4) * 4;
  const int nn = nBase + wc + col0;
  const float bv = bias[nn] + bias[DIH + nn] + bias[2*DIH + nn] + bias[3*DIH + nn];
  #pragma unroll
  for (int r = 0; r < 4; r++) {
    #pragma unroll
    for (int reg = 0; reg < 4; reg++) {
      const int m = mBase + wr + r*16 + row0 + reg;
      const float av = acc[r][0][reg] + acc[r][1][reg] + acc[r][2][reg] + acc[r][3][reg];
      outB[(size_t)m*DIH + nn] = f2b(geluf(av + bv));
    }
  }
}

// ---------------- fused scan: batch values pinned in VGPRs via asm keepalives ---------
// R11 found sched_barrier(0) does NOT stop IR-level sinking of pure FP computation
// (VGPR stayed 72). Fix per rule #17: asm volatile consumes+produces every batch value,
// forcing all 96 into VGPRs before the recurrence chain starts. LDS-read latencies then
// overlap within the batch (one exposure per tile, not 16 serial ones).
__launch_bounds__(256, 2)
__global__ void scan_v5(const float* __restrict__ bcg, const bf16* __restrict__ xi,
                        const bf16* __restrict__ gz, const bf16* __restrict__ dtp,
                        const float* __restrict__ A_log, const float* __restrict__ Dp,
                        const float* __restrict__ s0,
                        bf16* __restrict__ ypre, float* __restrict__ state_out)
{
  const int dg = blockIdx.x;
  const int tid = threadIdx.x;
  const int u = tid >> 7, ut = tid & 127;
  const int c = blockIdx.y*2 + u;
  const int dl = ut >> 3, ng = ut & 7;
  const int d0 = dg*16;
  const int d  = d0 + dl;
  const int base_m = c*PP;

  __shared__ float  bcT[2][3][16][36];   // B 0..15 | C 16..31, pitch 144B
  __shared__ ushort dtT[2][3][16][24];   // bf16 dt, pitch 48B
  __shared__ ushort xgT[2][3][16][40];   // xi 0..15 | gz 16..31, pitch 80B
  __shared__ float  ybF[2][2][16][17];
  __shared__ ushort outT[2][16][24];     // pitch 48B
  __shared__ float  DvT[2][16];

  if (ut < 16) DvT[u][ut] = Dp[d0 + ut];
  const float2 al = *(const float2*)&A_log[(size_t)d*NST + 2*ng];
  const float a20 = -__expf(al.x)*LOG2E;
  const float a21 = -__expf(al.y)*LOG2E;
  float2 s = *(const float2*)&s0[((size_t)c*DIH + d)*NST + 2*ng];

  // staging roles: all 128 threads 1 bcg float4; ut<96 one secondary uint4
  const int br = ut >> 3, bc4 = (ut & 7)*4;
  float4 bc_r; uint4 sec_r;

#define STAGE_LOAD(mm) do { \
    bc_r = *(const float4*)&bcg[(size_t)((mm) + br)*32 + bc4]; \
    if (ut < 32)      sec_r = *(const uint4*)&((const ushort*)dtp)[(size_t)((mm) + (ut>>1))*DIH + d0 + (ut&1)*8]; \
    else if (ut < 64) sec_r = *(const uint4*)&((const ushort*)xi)[(size_t)((mm) + ((ut-32)>>1))*DIH + d0 + ((ut-32)&1)*8]; \
    else if (ut < 96) sec_r = *(const uint4*)&((const ushort*)gz)[(size_t)((mm) + ((ut-64)>>1))*DIH + d0 + ((ut-64)&1)*8]; \
  } while(0)
#define STAGE_COMMIT(nbuf) do { \
    *(float4*)&bcT[u][nbuf][br][bc4] = bc_r; \
    if (ut < 32)      *(uint4*)&dtT[u][nbuf][ut>>1][(ut&1)*8] = sec_r; \
    else if (ut < 64) *(uint4*)&xgT[u][nbuf][(ut-32)>>1][((ut-32)&1)*8] = sec_r; \
    else if (ut < 96) *(uint4*)&xgT[u][nbuf][(ut-64)>>1][16 + ((ut-64)&1)*8] = sec_r; \
  } while(0)

  STAGE_LOAD(base_m);
  STAGE_COMMIT(0);
  __syncthreads();

  for (int g = 0; g < 16; ++g){
    const int buf = g % 3, nb = (g+1) % 3, yb = g & 1;
    const int m0 = base_m + g*16;
    if (g < 15) STAGE_LOAD(m0 + 16);
    // batch: pull tile data to registers, precompute decay/input terms
    float e0[16], e1[16], t0[16], t1[16], cx[16], cy[16];
    #pragma unroll
    for (int j = 0; j < 16; j++){
      const float dtv = us2f(dtT[u][buf][j][dl]);
      const float xiv = us2f(xgT[u][buf][j][dl]);
      const float2 Bv = *(const float2*)&bcT[u][buf][j][2*ng];
      const float2 Cv = *(const float2*)&bcT[u][buf][j][16 + 2*ng];
      const float dtxi = dtv * xiv;
      e0[j] = __builtin_amdgcn_exp2f(dtv*a20);
      e1[j] = __builtin_amdgcn_exp2f(dtv*a21);
      t0[j] = dtxi*Bv.x; t1[j] = dtxi*Bv.y;
      cx[j] = Cv.x;      cy[j] = Cv.y;
    }
    // rule #17: force every batch value into a VGPR HERE. The asm consumes and
    // reproduces each value, so no computation can sink past it (IR or MIR level).
    #pragma unroll
    for (int j = 0; j < 16; j++){
      asm volatile("" : "+v"(e0[j]), "+v"(e1[j]), "+v"(t0[j]),
                        "+v"(t1[j]), "+v"(cx[j]), "+v"(cy[j]));
    }
    // 16-step recurrence: pure fma chain; y/DPP tree hangs off it
    #pragma unroll
    for (int j = 0; j < 16; j++){
      s.x = fmaf(s.x, e0[j], t0[j]);
      s.y = fmaf(s.y, e1[j], t1[j]);
      float y = fmaf(s.y, cy[j], s.x*cx[j]);
      int t;
      t = __builtin_amdgcn_update_dpp(0, __float_as_int(y), 0x111, 0xf, 0xf, true);
      y += __int_as_float(t);
      t = __builtin_amdgcn_update_dpp(0, __float_as_int(y), 0x112, 0xf, 0xf, true);
      y += __int_as_float(t);
      t = __builtin_amdgcn_update_dpp(0, __float_as_int(y), 0x114, 0xf, 0xf, true);
      y += __int_as_float(t);
      if (ng == 7) ybF[u][yb][j][dl] = y;     // clean 8-lane group sum at lane 7/15
    }
    if (g < 15) STAGE_COMMIT(nb);
    __syncthreads();
    // epilogue: thread (ej=ut>>3, eg=ut&7) -> outputs (m0+ej, d0+2eg..2eg+1)
    {
      const int ej = ut >> 3, eg = ut & 7;
      #pragma unroll
      for (int q = 0; q < 2; q++){
        const int ed = 2*eg + q;
        bf16 hv = f2b((ybF[u][yb][ej][ed] + DvT[u][ed]*us2f(xgT[u][buf][ej][ed]))
                      * us2f(xgT[u][buf][ej][16+ed]));
        outT[u][ej][ed] = *(const ushort*)&hv;
      }
      if (eg < 2)
        *(uint4*)((ushort*)ypre + (size_t)(m0+ej)*DIH + d0 + eg*8) = *(const uint4*)&outT[u][ej][eg*8];
    }
  }
  *(float2*)&state_out[((size_t)c*DIH + d)*NST + 2*ng] = s;
#undef STAGE_LOAD
#undef STAGE_COMMIT
}

extern "C" void kernel_launch(void* const* d_in, const int* in_sizes, int n_in,
                              void* d_out, int out_size, void* d_ws, size_t ws_size,
                              hipStream_t stream) {
  const float* x       = (const float*)d_in[0];
  const float* s0      = (const float*)d_in[1];
  const float* in_w    = (const float*)d_in[2];
  const float* in_b    = (const float*)d_in[3];
  const float* conv_w  = (const float*)d_in[4];
  const float* conv_b  = (const float*)d_in[5];
  const float* param_w = (const float*)d_in[6];
  const float* param_b = (const float*)d_in[7];
  const float* dt_w    = (const float*)d_in[8];
  const float* dt_b    = (const float*)d_in[9];
  const float* out_w   = (const float*)d_in[10];
  const float* out_b   = (const float*)d_in[11];
  const float* A_log   = (const float*)d_in[12];
  const float* Dp      = (const float*)d_in[13];

  char* ws = (char*)d_ws;
  bf16*   xi    = (bf16*)ws;   ws += (size_t)MM*DIH*2;     //  8 MB
  bf16*   gz    = (bf16*)ws;   ws += (size_t)MM*DIH*2;     //  8 MB
  float*  bcg   = (float*)ws;  ws += (size_t)MM*32*4;      // 0.5 MB (B|C fp32)
  bf16*   xdbb  = (bf16*)ws;   ws += (size_t)MM*64*2;      // 0.5 MB (dt GEMM A)
  float*  cb2p  = (float*)ws;  ws += 4*DIH*4;              // 16 KB (cb2 partials)
  bf16*   ypre  = (bf16*)ws;   ws += (size_t)MM*DIH*2;     //  8 MB
  bf16*   outwb = (bf16*)ws;   ws += (size_t)DMH*DIH*2;    //  1 MB
  bf16*   pwb   = (bf16*)ws;   ws += (size_t)64*DIH*2;     // 128 KB
  bf16*   dtwb  = (bf16*)ws;   ws += (size_t)DIH*64*2;     // 128 KB
  char*   U     = ws;          ws += (size_t)32*1024*1024; // union region, 32 MB
  // early tenants of U:
  bf16* Wfb  = (bf16*)(U);                                 // dead after conv
  bf16* xbf  = (bf16*)(U + (size_t) 4*1024*1024);          // dead after conv
  bf16* inwz = (bf16*)(U + (size_t) 8*1024*1024);
  bf16* inwT = (bf16*)(U + (size_t) 9*1024*1024);
  bf16* cwT  = (bf16*)(U + (size_t)10*1024*1024);          // dead after fold GEMM
  // late tenant of U:
  bf16*  dtp = (bf16*)(U + (size_t)16*1024*1024);          // 8 MB bf16 dt plane

  float* y_out  = (float*)d_out;                           // [C,P,DM] fp32
  float* st_out = y_out + (size_t)MM*DMH;                  // [C,DI,16] fp32

  // fused prep (casts, conv repack + cb2p partials, transpose, dt_w cast)
  prep_all<<<7424, 256, 0, stream>>>(x, in_w, out_w, param_w, conv_w, dt_w,
                                     in_b, conv_b, cb2p,
                                     xbf, inwz, outwb, pwb, cwT, inwT, dtwb);

  // fold: Wf[k][o][m] = sum_i conv_w[o,i,k]*in_w[i,m]   (4 taps via grid.z)
  mfma_gemm<3,1><<<dim3(DIH/128, DMH/32, 4), 256, 0, stream>>>(
      cwT, DIH, inwT, DIH, nullptr, nullptr, Wfb, 4*DMH, DIH, DIH*DIH, DMH, 0);
  // z-half in_proj: gelu(gelu(x @ in_w_z^T + b_z)) -> gz (contiguous bf16)
  mfma_gemm<2,1><<<dim3(MM/128, DIH/32), 256, 0, stream>>>(
      xbf, DMH, inwz, DMH, in_b + DIH, nullptr, gz, DIH, DMH, 0, 0, 0);
  // fused conv via halo-tiled kernel (A staged once, 4 tap-accumulators, cb2p bias)
  mfma_conv<<<dim3(MM/128, DIH/32), 256, 0, stream>>>(xbf, Wfb, cb2p, xi);
  // x_db = xi @ param_w.T + param_b  (single-pass K=1024, fused epilogue:
  //   cols 0..31 -> xdbb bf16 (+zero pad), cols 32..63 -> bcg fp32)
  mfma_gemm<7,1><<<dim3(MM/128, 2), 256, 0, stream>>>(
      xi, DIH, pwb, DIH, param_b, bcg, (bf16*)xdbb, 64, DIH, 0, 0, 0);
  // dtp[m][d] = bf16( softplus(dt_in @ dt_w^T + dt_b) )  via MFMA
  mfma_gemm<5,1><<<dim3(MM/128, DIH/32), 256, 0, stream>>>(
      xdbb, 64, dtwb, 64, dt_b, nullptr, (bf16*)dtp, DIH, 64, 0, 0, 0);
  // fused scan, 2 states/lane, 2 units/block, batch pinned via asm keepalives
  scan_v5<<<dim3(64, CC/2), 256, 0, stream>>>(bcg, xi, gz, dtp, A_log, Dp,
                                              s0, ypre, st_out);
  // out projection
  mfma_gemm<0,1><<<dim3(MM/128, DMH/32), 256, 0, stream>>>(
      ypre, DIH, outwb, DIH, out_b, y_out, nullptr, DMH, DIH, 0, 0, 0);
}

// Round 13
// 213.781 us; speedup vs baseline: 1.0295x; 1.0295x over previous
//
#include <hip/hip_runtime.h>
#include <hip/hip_bf16.h>

typedef __hip_bfloat16 bf16;
typedef short bf16x8 __attribute__((ext_vector_type(8)));
typedef float f32x4 __attribute__((ext_vector_type(4)));

#define CC 16
#define PP 256
#define DMH 512
#define DIH 1024
#define MM (CC*PP)   /* 4096 rows (c,p) */
#define NST 16
#define NDT 32
#define LOG2E 1.44269504088896f

__device__ __forceinline__ float b2f(bf16 v){ return __bfloat162float(v); }
__device__ __forceinline__ bf16  f2b(float v){ return __float2bfloat16(v); }
__device__ __forceinline__ float us2f(ushort u){ bf16 h; *(ushort*)&h = u; return __bfloat162float(h); }

// fast tanh-gelu: tanh(u) = 1 - 2/(exp(2u)+1); exact limits at +-inf
__device__ __forceinline__ float geluf(float x){
  const float u = x*(0.7978845608028654f + 0.035677408136300125f*x*x);
  const float e = __builtin_amdgcn_exp2f(2.885390081777927f*u);   // exp(2u)
  const float t = 1.0f - 2.0f*__builtin_amdgcn_rcpf(e + 1.0f);
  return 0.5f*x*(1.0f + t);
}
// softplus via v_exp/v_log: ln(1+e^x) = ln2 * log2(1 + exp2(x*log2e))
__device__ __forceinline__ float softplusf(float x){
  if (x > 20.0f) return x;
  const float e = __builtin_amdgcn_exp2f(x * LOG2E);
  return 0.6931471805599453f * __builtin_amdgcn_logf(1.0f + e);
}

__device__ __forceinline__ void g2l16(const bf16* g, bf16* l){
  __builtin_amdgcn_global_load_lds(
      (const __attribute__((address_space(1))) void*)g,
      (__attribute__((address_space(3))) void*)(uint32_t)(uintptr_t)l,
      16, 0, 0);
}

// ---------------- fused prep: casts + conv repack (+cb2p partials) + transpose + dtw --
__global__ void prep_all(const float* __restrict__ x, const float* __restrict__ in_w,
                         const float* __restrict__ out_w, const float* __restrict__ param_w,
                         const float* __restrict__ conv_w, const float* __restrict__ dt_w,
                         const float* __restrict__ in_b, const float* __restrict__ conv_b,
                         float* __restrict__ cb2p,
                         bf16* __restrict__ xbf, bf16* __restrict__ inwz,
                         bf16* __restrict__ outwb, bf16* __restrict__ pwb,
                         bf16* __restrict__ cwT, bf16* __restrict__ inwT,
                         bf16* __restrict__ dtwb)
{
  const int b = blockIdx.x, tid = threadIdx.x;
  if (b < 3136){
    const float* src; bf16* dst; int i;
    if (b < 2048)      { src = x;                       dst = xbf;   i = b*256 + tid; }
    else if (b < 2560) { src = in_w + (size_t)DIH*DMH;  dst = inwz;  i = (b-2048)*256 + tid; }
    else if (b < 3072) { src = out_w;                   dst = outwb; i = (b-2560)*256 + tid; }
    else               { src = param_w;                 dst = pwb;   i = (b-3072)*256 + tid; }
    float4 v = ((const float4*)src)[i];
    bf16 o[4] = {f2b(v.x), f2b(v.y), f2b(v.z), f2b(v.w)};
    *(ushort4*)&dst[(size_t)i*4] = *(const ushort4*)o;
  } else if (b < 7232){
    const size_t idx = (size_t)(b-3136)*256 + tid;      // o*1024 + i
    const float4 v = *(const float4*)(conv_w + idx*4);  // [o][i][tap] -> [tap][o][i]
    cwT[idx]                     = f2b(v.x);
    cwT[(size_t)DIH*DIH   + idx] = f2b(v.y);
    cwT[(size_t)2*DIH*DIH + idx] = f2b(v.z);
    cwT[(size_t)3*DIH*DIH + idx] = f2b(v.w);
    // folded bias partial (no atomics): cb2p[sub][o] = sum over this block's i-range
    __shared__ float ls[4];
    const int i = (int)(idx & 1023);
    float acc = (v.x + v.y + v.z + v.w) * in_b[i];
    for (int off = 32; off; off >>= 1) acc += __shfl_down(acc, off);
    if ((tid & 63) == 0) ls[tid >> 6] = acc;
    __syncthreads();
    if (tid == 0){
      const int o   = (int)(idx >> 10);
      const int sub = (b - 3136) & 3;
      float tot = ls[0] + ls[1] + ls[2] + ls[3];
      if (sub == 0) tot += conv_b[o];
      cb2p[sub*DIH + o] = tot;
    }
  } else if (b < 7360){
    // in_w xi-half [i<1024][m<512] -> inwT [m][i], 64x64 LDS tile
    __shared__ float T[64][65];
    const int b2 = b - 7232;
    const int i0 = (b2 >> 3)*64, m0 = (b2 & 7)*64;
    const int r = tid >> 2, c0 = (tid & 3)*16;
    #pragma unroll
    for (int t = 0; t < 4; t++){
      float4 v = *(const float4*)&in_w[(size_t)(i0 + r)*DMH + m0 + c0 + t*4];
      T[r][c0+t*4+0] = v.x; T[r][c0+t*4+1] = v.y;
      T[r][c0+t*4+2] = v.z; T[r][c0+t*4+3] = v.w;
    }
    __syncthreads();
    bf16 o[16];
    #pragma unroll
    for (int t = 0; t < 16; t++) o[t] = f2b(T[c0 + t][r]);
    *(ushort4*)&inwT[(size_t)(m0 + r)*DIH + i0 + c0]      = *(const ushort4*)&o[0];
    *(ushort4*)&inwT[(size_t)(m0 + r)*DIH + i0 + c0 + 4]  = *(const ushort4*)&o[4];
    *(ushort4*)&inwT[(size_t)(m0 + r)*DIH + i0 + c0 + 8]  = *(const ushort4*)&o[8];
    *(ushort4*)&inwT[(size_t)(m0 + r)*DIH + i0 + c0 + 12] = *(const ushort4*)&o[12];
  } else {
    // dt_w [1024][32] fp32 -> dtwb [1024][64] bf16, cols 32..63 zero (K=64 pad)
    const int idx4 = (b-7360)*256 + tid;          // 0..16383
    const int d = idx4 >> 4, k4 = (idx4 & 15)*4;
    bf16 o[4] = {};
    if (k4 < 32){
      const float4 v = *(const float4*)&dt_w[(size_t)d*NDT + k4];
      o[0]=f2b(v.x); o[1]=f2b(v.y); o[2]=f2b(v.z); o[3]=f2b(v.w);
    }
    *(ushort4*)&dtwb[(size_t)d*64 + k4] = *(const ushort4*)o;
  }
}

// ---------------- MFMA GEMM: C[m,n] = epi( sum_k A[m,k]*B[n,k] + bias[n] ) -------------
// LDS XOR-swizzle (T2, gload_lds-compatible): linear LDS dest, pre-swizzled global
// source chunk, same XOR on the ds_read side.
#define TBK 64

template<int EPI, int NFRAG>
__launch_bounds__(256)
__global__ void mfma_gemm(const bf16* __restrict__ A, int lda,
                          const bf16* __restrict__ B, int ldb,
                          const float* __restrict__ bias,
                          float* __restrict__ outF,
                          bf16* __restrict__ outB0,
                          int ldo, int K, int azs, int ozs, int kzs)
{
  __shared__ bf16 As[128*TBK];           // 16 KB
  __shared__ bf16 Bs[32*NFRAG*TBK];      // 4/8 KB
  const int tid  = threadIdx.x;
  const int lane = tid & 63;
  const int wave = tid >> 6;
  const int wr = (wave >> 1) * 64;
  const int wc = (wave & 1) * 16 * NFRAG;
  const int mBase = blockIdx.x * 128;
  const int nBase = blockIdx.y * (32*NFRAG);
  A += (size_t)blockIdx.z * azs;
  const int nOff = blockIdx.z * ozs;
  const int koff = blockIdx.z * kzs;

  f32x4 acc[4][NFRAG] = {};

  for (int k0 = 0; k0 < K; k0 += TBK) {
    __syncthreads();
    #pragma unroll
    for (int it = 0; it < 4; it++) {      // As: 1024 chunks of 16B
      const int idx = it*256 + tid;
      const int r = idx >> 3;
      const int cs = (idx & 7) ^ (r & 7);         // pre-swizzled source chunk
      const bf16* ga = A + (size_t)(mBase + r)*lda + koff + k0 + cs*8;
      g2l16(ga, &As[(size_t)idx*8]);
    }
    #pragma unroll
    for (int it = 0; it < NFRAG; it++) {  // Bs: 256*NFRAG chunks of 16B
      const int idx = it*256 + tid;
      const int r = idx >> 3;
      const int cs = (idx & 7) ^ (r & 7);
      const bf16* gb = B + (size_t)(nBase + r)*ldb + koff + k0 + cs*8;
      g2l16(gb, &Bs[(size_t)idx*8]);
    }
    __syncthreads();
    #pragma unroll
    for (int ks = 0; ks < 2; ks++) {
      bf16x8 af[4], bfr[NFRAG];
      #pragma unroll
      for (int r = 0; r < 4; r++){
        const int rr = wr + r*16 + (lane & 15);
        const int ch = (ks*4 + (lane>>4)) ^ (rr & 7);
        af[r] = *(const bf16x8*)&As[rr*TBK + ch*8];
      }
      #pragma unroll
      for (int c = 0; c < NFRAG; c++){
        const int rn = wc + c*16 + (lane & 15);
        const int ch = (ks*4 + (lane>>4)) ^ (rn & 7);
        bfr[c] = *(const bf16x8*)&Bs[rn*TBK + ch*8];
      }
      #pragma unroll
      for (int r = 0; r < 4; r++)
        #pragma unroll
        for (int c = 0; c < NFRAG; c++)
          acc[r][c] = __builtin_amdgcn_mfma_f32_16x16x32_bf16(af[r], bfr[c], acc[r][c], 0, 0, 0);
    }
  }

  const int col0 = lane & 15;
  const int row0 = (lane >> 4) * 4;
  #pragma unroll
  for (int r = 0; r < 4; r++) {
    #pragma unroll
    for (int c = 0; c < NFRAG; c++) {
      #pragma unroll
      for (int reg = 0; reg < 4; reg++) {
        const int m = mBase + wr + r*16 + row0 + reg;
        const int n = nBase + wc + c*16 + col0;
        const float av = acc[r][c][reg];
        if (EPI == 0) {
          outF[(size_t)m*ldo + n] = av + bias[n];
        } else if (EPI == 2) {
          outB0[(size_t)m*ldo + n] = f2b(geluf(geluf(av + bias[n])));
        } else if (EPI == 3) {
          outB0[(size_t)m*ldo + n + nOff] = f2b(av);
        } else if (EPI == 5) {
          // dt = softplus(av + dt_b[n]) -> bf16 dt-only plane (dt*xi done in scan)
          const float dtv = softplusf(av + bias[n]);
          bf16 dh = f2b(dtv);
          ((ushort*)outB0)[(size_t)m*ldo + n] = *(const ushort*)&dh;
        } else if (EPI == 7) {
          // fused param epilogue: n<32 -> xdbb (bf16 dt-GEMM input);
          // n>=32 -> bcg (fp32 B|C) + zero-pad xdbb col (K=64 pad for dt GEMM)
          const float vv = av + bias[n];
          if (n < 32) {
            bf16 dh = f2b(vv);
            ((ushort*)outB0)[(size_t)m*64 + n] = *(const ushort*)&dh;
          } else {
            ((ushort*)outB0)[(size_t)m*64 + n] = 0;
            outF[(size_t)m*32 + (n - 32)] = vv;
          }
        }
      }
    }
  }
}

// ---------------- halo-tiled conv GEMM: xi = gelu( sum_tap x[clamp]@Wf_tap^T + cb2 ) ---
__launch_bounds__(256)
__global__ void mfma_conv(const bf16* __restrict__ A,   // xbf [4096][512]
                          const bf16* __restrict__ B,   // Wfb [1024][4*512] (o, tap*512+m)
                          const float* __restrict__ bias, // cb2p [4][1024]
                          bf16* __restrict__ outB)      // xi [4096][1024]
{
  __shared__ bf16 As[132*64];        // halo rows h=0..131 -> p = clamp(q-2+h, 0, 255)
  __shared__ bf16 Bs[128*64];        // (tap*32+o) x 64
  const int tid = threadIdx.x;
  const int lane = tid & 63;
  const int wave = tid >> 6;
  const int wr = (wave >> 1) * 64;
  const int wc = (wave & 1) * 16;
  const int mBase = blockIdx.x * 128;
  const int nBase = blockIdx.y * 32;
  const int cc = mBase >> 8;
  const int q  = mBase & 255;

  f32x4 acc[4][4] = {};   // [r][tap]

  for (int k0 = 0; k0 < DMH; k0 += 64) {
    __syncthreads();
    // stage A halo: 132 rows x 8 chunks = 1056 (swizzle keyed on halo row h)
    #pragma unroll
    for (int it = 0; it < 5; it++) {
      const int idx = it*256 + tid;
      if (it < 4 || idx < 1056) {
        const int h = idx >> 3;
        const int cs = (idx & 7) ^ (h & 7);
        int p = q - 2 + h;
        p = min(max(p, 0), PP-1);
        g2l16(A + ((size_t)(cc*PP + p))*DMH + k0 + cs*8, &As[(size_t)idx*8]);
      }
    }
    // stage B: rows (tap*32+o), 128 x 8 chunks = 1024
    #pragma unroll
    for (int it = 0; it < 4; it++) {
      const int idx = it*256 + tid;
      const int r = idx >> 3;             // tap*32 + o
      const int tap = r >> 5, o = r & 31;
      const int cs = (idx & 7) ^ (r & 7);
      g2l16(B + (size_t)(nBase + o)*(4*DMH) + tap*DMH + k0 + cs*8, &Bs[(size_t)idx*8]);
    }
    __syncthreads();
    #pragma unroll
    for (int ks = 0; ks < 2; ks++) {
      #pragma unroll
      for (int t = 0; t < 4; t++) {
        bf16x8 bft;
        {
          const int rn = t*32 + wc + (lane & 15);
          const int ch = (ks*4 + (lane>>4)) ^ (rn & 7);
          bft = *(const bf16x8*)&Bs[rn*64 + ch*8];
        }
        #pragma unroll
        for (int r = 0; r < 4; r++) {
          const int h = wr + r*16 + (lane & 15) + t;   // output row m_local + tap
          const int ch = (ks*4 + (lane>>4)) ^ (h & 7);
          bf16x8 af = *(const bf16x8*)&As[h*64 + ch*8];
          acc[r][t] = __builtin_amdgcn_mfma_f32_16x16x32_bf16(af, bft, acc[r][t], 0, 0, 0);
        }
      }
    }
  }
  const int col0 = lane & 15;
  const int row0 = (lane >> 4) * 4;
  const int nn = nBase + wc + col0;
  const float bv = bias[nn] + bias[DIH + nn] + bias[2*DIH + nn] + bias[3*DIH + nn];
  #pragma unroll
  for (int r = 0; r < 4; r++) {
    #pragma unroll
    for (int reg = 0; reg < 4; reg++) {
      const int m = mBase + wr + r*16 + row0 + reg;
      const float av = acc[r][0][reg] + acc[r][1][reg] + acc[r][2][reg] + acc[r][3][reg];
      outB[(size_t)m*DIH + nn] = f2b(geluf(av + bv));
    }
  }
}

// ---------------- fused scan v6: TRANSPOSED LDS -> vector ds_reads --------------------
// R12 diagnosis: scan was LDS-instruction-issue bound (64 reads/thread/tile, mostly
// scalar u16 / strided b64; ~22us of pure LDS issue). v6 transposes dt/xi to [d][j]
// and B|C to [n][j] so each thread's per-tile reads are contiguous: 2+2 uint4 (dt,xi)
// + 16 float4 (B,C) = 20 vector reads. Staging commits become small scalar scatters.
__launch_bounds__(256, 2)
__global__ void scan_v6(const float* __restrict__ bcg, const bf16* __restrict__ xi,
                        const bf16* __restrict__ gz, const bf16* __restrict__ dtp,
                        const float* __restrict__ A_log, const float* __restrict__ Dp,
                        const float* __restrict__ s0,
                        bf16* __restrict__ ypre, float* __restrict__ state_out)
{
  const int dg = blockIdx.x;
  const int tid = threadIdx.x;
  const int u = tid >> 7, ut = tid & 127;
  const int c = blockIdx.y*2 + u;
  const int dl = ut >> 3, ng = ut & 7;
  const int d0 = dg*16;
  const int d  = d0 + dl;
  const int base_m = c*PP;

  __shared__ float  bcT[2][3][32][20];   // transposed: row n (B 0-15 | C 16-31) x j, pitch 80B
  __shared__ ushort dtT[2][3][16][24];   // transposed: [d][j], pitch 48B
  __shared__ ushort xiT[2][3][16][24];   // transposed: [d][j]
  __shared__ ushort gzT[2][3][16][24];   // row-major [j][d]
  __shared__ float  ybF[2][2][16][17];
  __shared__ ushort outT[2][16][24];
  __shared__ float  DvT[2][16];

  if (ut < 16) DvT[u][ut] = Dp[d0 + ut];
  const float2 al = *(const float2*)&A_log[(size_t)d*NST + 2*ng];
  const float a20 = -__expf(al.x)*LOG2E;
  const float a21 = -__expf(al.y)*LOG2E;
  float2 s = *(const float2*)&s0[((size_t)c*DIH + d)*NST + 2*ng];

  // staging roles: all 128 threads 1 bcg float4; ut<96 one secondary uint4
  const int br = ut >> 3, bc4 = (ut & 7)*4;
  float4 bc_r; uint4 sec_r;

#define STAGE_LOAD(mm) do { \
    bc_r = *(const float4*)&bcg[(size_t)((mm) + br)*32 + bc4]; \
    if (ut < 32)      sec_r = *(const uint4*)&((const ushort*)dtp)[(size_t)((mm) + (ut>>1))*DIH + d0 + (ut&1)*8]; \
    else if (ut < 64) sec_r = *(const uint4*)&((const ushort*)xi)[(size_t)((mm) + ((ut-32)>>1))*DIH + d0 + ((ut-32)&1)*8]; \
    else if (ut < 96) sec_r = *(const uint4*)&((const ushort*)gz)[(size_t)((mm) + ((ut-64)>>1))*DIH + d0 + ((ut-64)&1)*8]; \
  } while(0)
// transposed commits: bc scatters 4 floats to [n][j]; dt/xi scatter 8 u16 to [d][j];
// gz stays row-major vector store.
#define STAGE_COMMIT(nbuf) do { \
    bcT[u][nbuf][bc4+0][br] = bc_r.x; \
    bcT[u][nbuf][bc4+1][br] = bc_r.y; \
    bcT[u][nbuf][bc4+2][br] = bc_r.z; \
    bcT[u][nbuf][bc4+3][br] = bc_r.w; \
    if (ut < 32){ \
      const int jj = ut >> 1, hh = (ut & 1)*8; \
      _Pragma("unroll") \
      for (int t = 0; t < 8; t++) dtT[u][nbuf][hh+t][jj] = ((const ushort*)&sec_r)[t]; \
    } else if (ut < 64){ \
      const int jj = (ut-32) >> 1, hh = ((ut-32) & 1)*8; \
      _Pragma("unroll") \
      for (int t = 0; t < 8; t++) xiT[u][nbuf][hh+t][jj] = ((const ushort*)&sec_r)[t]; \
    } else if (ut < 96){ \
      *(uint4*)&gzT[u][nbuf][(ut-64)>>1][((ut-64)&1)*8] = sec_r; \
    } \
  } while(0)

  STAGE_LOAD(base_m);
  STAGE_COMMIT(0);
  __syncthreads();

  for (int g = 0; g < 16; ++g){
    const int buf = g % 3, nb = (g+1) % 3, yb = g & 1;
    const int m0 = base_m + g*16;
    if (g < 15) STAGE_LOAD(m0 + 16);
    // vector-load this thread's transposed rows (20 LDS reads total)
    uint4 dtv4[2], xiv4[2];
    dtv4[0] = *(const uint4*)&dtT[u][buf][dl][0];
    dtv4[1] = *(const uint4*)&dtT[u][buf][dl][8];
    xiv4[0] = *(const uint4*)&xiT[u][buf][dl][0];
    xiv4[1] = *(const uint4*)&xiT[u][buf][dl][8];
    float4 Bv0[4], Bv1[4], Cv0[4], Cv1[4];
    #pragma unroll
    for (int cc = 0; cc < 4; cc++){
      Bv0[cc] = *(const float4*)&bcT[u][buf][2*ng    ][cc*4];
      Bv1[cc] = *(const float4*)&bcT[u][buf][2*ng+1  ][cc*4];
      Cv0[cc] = *(const float4*)&bcT[u][buf][16+2*ng ][cc*4];
      Cv1[cc] = *(const float4*)&bcT[u][buf][17+2*ng ][cc*4];
    }
    // batch: decay/input terms from registers
    float e0[16], e1[16], t0[16], t1[16];
    #pragma unroll
    for (int j = 0; j < 16; j++){
      const float dtv = us2f(((const ushort*)dtv4)[j]);
      const float xiv = us2f(((const ushort*)xiv4)[j]);
      const float dtxi = dtv * xiv;
      e0[j] = __builtin_amdgcn_exp2f(dtv*a20);
      e1[j] = __builtin_amdgcn_exp2f(dtv*a21);
      t0[j] = dtxi * ((const float*)Bv0)[j];
      t1[j] = dtxi * ((const float*)Bv1)[j];
    }
    // 16-step recurrence: pure fma chain; y/DPP tree hangs off it
    #pragma unroll
    for (int j = 0; j < 16; j++){
      s.x = fmaf(s.x, e0[j], t0[j]);
      s.y = fmaf(s.y, e1[j], t1[j]);
      float y = fmaf(s.y, ((const float*)Cv1)[j], s.x*((const float*)Cv0)[j]);
      int t;
      t = __builtin_amdgcn_update_dpp(0, __float_as_int(y), 0x111, 0xf, 0xf, true);
      y += __int_as_float(t);
      t = __builtin_amdgcn_update_dpp(0, __float_as_int(y), 0x112, 0xf, 0xf, true);
      y += __int_as_float(t);
      t = __builtin_amdgcn_update_dpp(0, __float_as_int(y), 0x114, 0xf, 0xf, true);
      y += __int_as_float(t);
      if (ng == 7) ybF[u][yb][j][dl] = y;     // clean 8-lane group sum at lane 7/15
    }
    if (g < 15) STAGE_COMMIT(nb);
    __syncthreads();
    // epilogue: thread (ej=ut>>3, eg=ut&7) -> outputs (m0+ej, d0+2eg..2eg+1)
    {
      const int ej = ut >> 3, eg = ut & 7;
      #pragma unroll
      for (int q = 0; q < 2; q++){
        const int ed = 2*eg + q;
        bf16 hv = f2b((ybF[u][yb][ej][ed] + DvT[u][ed]*us2f(xiT[u][buf][ed][ej]))
                      * us2f(gzT[u][buf][ej][ed]));
        outT[u][ej][ed] = *(const ushort*)&hv;
      }
      if (eg < 2)
        *(uint4*)((ushort*)ypre + (size_t)(m0+ej)*DIH + d0 + eg*8) = *(const uint4*)&outT[u][ej][eg*8];
    }
  }
  *(float2*)&state_out[((size_t)c*DIH + d)*NST + 2*ng] = s;
#undef STAGE_LOAD
#undef STAGE_COMMIT
}

extern "C" void kernel_launch(void* const* d_in, const int* in_sizes, int n_in,
                              void* d_out, int out_size, void* d_ws, size_t ws_size,
                              hipStream_t stream) {
  const float* x       = (const float*)d_in[0];
  const float* s0      = (const float*)d_in[1];
  const float* in_w    = (const float*)d_in[2];
  const float* in_b    = (const float*)d_in[3];
  const float* conv_w  = (const float*)d_in[4];
  const float* conv_b  = (const float*)d_in[5];
  const float* param_w = (const float*)d_in[6];
  const float* param_b = (const float*)d_in[7];
  const float* dt_w    = (const float*)d_in[8];
  const float* dt_b    = (const float*)d_in[9];
  const float* out_w   = (const float*)d_in[10];
  const float* out_b   = (const float*)d_in[11];
  const float* A_log   = (const float*)d_in[12];
  const float* Dp      = (const float*)d_in[13];

  char* ws = (char*)d_ws;
  bf16*   xi    = (bf16*)ws;   ws += (size_t)MM*DIH*2;     //  8 MB
  bf16*   gz    = (bf16*)ws;   ws += (size_t)MM*DIH*2;     //  8 MB
  float*  bcg   = (float*)ws;  ws += (size_t)MM*32*4;      // 0.5 MB (B|C fp32)
  bf16*   xdbb  = (bf16*)ws;   ws += (size_t)MM*64*2;      // 0.5 MB (dt GEMM A)
  float*  cb2p  = (float*)ws;  ws += 4*DIH*4;              // 16 KB (cb2 partials)
  bf16*   ypre  = (bf16*)ws;   ws += (size_t)MM*DIH*2;     //  8 MB
  bf16*   outwb = (bf16*)ws;   ws += (size_t)DMH*DIH*2;    //  1 MB
  bf16*   pwb   = (bf16*)ws;   ws += (size_t)64*DIH*2;     // 128 KB
  bf16*   dtwb  = (bf16*)ws;   ws += (size_t)DIH*64*2;     // 128 KB
  char*   U     = ws;          ws += (size_t)32*1024*1024; // union region, 32 MB
  // early tenants of U:
  bf16* Wfb  = (bf16*)(U);                                 // dead after conv
  bf16* xbf  = (bf16*)(U + (size_t) 4*1024*1024);          // dead after conv
  bf16* inwz = (bf16*)(U + (size_t) 8*1024*1024);
  bf16* inwT = (bf16*)(U + (size_t) 9*1024*1024);
  bf16* cwT  = (bf16*)(U + (size_t)10*1024*1024);          // dead after fold GEMM
  // late tenant of U:
  bf16*  dtp = (bf16*)(U + (size_t)16*1024*1024);          // 8 MB bf16 dt plane

  float* y_out  = (float*)d_out;                           // [C,P,DM] fp32
  float* st_out = y_out + (size_t)MM*DMH;                  // [C,DI,16] fp32

  // fused prep (casts, conv repack + cb2p partials, transpose, dt_w cast)
  prep_all<<<7424, 256, 0, stream>>>(x, in_w, out_w, param_w, conv_w, dt_w,
                                     in_b, conv_b, cb2p,
                                     xbf, inwz, outwb, pwb, cwT, inwT, dtwb);

  // fold: Wf[k][o][m] = sum_i conv_w[o,i,k]*in_w[i,m]   (4 taps via grid.z)
  mfma_gemm<3,1><<<dim3(DIH/128, DMH/32, 4), 256, 0, stream>>>(
      cwT, DIH, inwT, DIH, nullptr, nullptr, Wfb, 4*DMH, DIH, DIH*DIH, DMH, 0);
  // z-half in_proj: gelu(gelu(x @ in_w_z^T + b_z)) -> gz (contiguous bf16)
  mfma_gemm<2,1><<<dim3(MM/128, DIH/32), 256, 0, stream>>>(
      xbf, DMH, inwz, DMH, in_b + DIH, nullptr, gz, DIH, DMH, 0, 0, 0);
  // fused conv via halo-tiled kernel (A staged once, 4 tap-accumulators, cb2p bias)
  mfma_conv<<<dim3(MM/128, DIH/32), 256, 0, stream>>>(xbf, Wfb, cb2p, xi);
  // x_db = xi @ param_w.T + param_b  (single-pass K=1024, fused epilogue:
  //   cols 0..31 -> xdbb bf16 (+zero pad), cols 32..63 -> bcg fp32)
  mfma_gemm<7,1><<<dim3(MM/128, 2), 256, 0, stream>>>(
      xi, DIH, pwb, DIH, param_b, bcg, (bf16*)xdbb, 64, DIH, 0, 0, 0);
  // dtp[m][d] = bf16( softplus(dt_in @ dt_w^T + dt_b) )  via MFMA
  mfma_gemm<5,1><<<dim3(MM/128, DIH/32), 256, 0, stream>>>(
      xdbb, 64, dtwb, 64, dt_b, nullptr, (bf16*)dtp, DIH, 64, 0, 0, 0);
  // fused scan v6: transposed LDS, vector ds_reads (20/thread/tile vs 64)
  scan_v6<<<dim3(64, CC/2), 256, 0, stream>>>(bcg, xi, gz, dtp, A_log, Dp,
                                              s0, ypre, st_out);
  // out projection
  mfma_gemm<0,1><<<dim3(MM/128, DMH/32), 256, 0, stream>>>(
      ypre, DIH, outwb, DIH, out_b, y_out, nullptr, DMH, DIH, 0, 0, 0);
}